// Round 4
// baseline (1090.462 us; speedup 1.0000x reference)
//
#include <hip/hip_runtime.h>
#include <cstdint>
#include <cstddef>

// RNN: B=256, T=512, H=512, I=64, O=24. fp32 in/out.
//
// v4 structure:
//  Path A2 (ws >= 257 MiB): K-split x2 across paired blocks.
//    1) xp_gemm: xp = W_ih x + b_ih + b_hh (f16, permuted) -> ws[0,128Mi);
//       also zeroes the sync counters.
//    2) rnn_core2: 32 blocks = (kb in {0,1}) x (g in 0..15). Block (kb,g)
//       computes partials over k in [256kb, 256kb+256) for ALL 512 h-cols of
//       batch group g. A-frags all in regs (128/lane). Per step, the 4 waves
//       owning the OTHER k-half's cols store f32 partials to d_ws (+release
//       counter, agent scope); the 4 "finalizer" waves spin on the partner's
//       counter (acquire), add partner partials + xp, tanh, write their h
//       half to LDS (double-buffered) and to hall. Partner = bid^16 (same
//       XCD under round-robin; correctness independent of mapping).
//    3) out_all: full-chip epilogue out = tanh(h_all @ W_ho^T + b_ho).
//  Path A (ws >= 256 MiB): round-3 single-CU persistent kernel.
//  Path C: self-contained fallback.

#define TSTEPS 512
#define HDIM   512
#define NIN    64
#define NOUT   24
#define BB     16
#define HPAD   520
#define XPAD   72
#define KHALF  256
#define HPAD2  264      // k-local h pitch (h16) for rnn_core2
// Path A split
#define NREG   49
#define NLDS   (64 - NREG)

typedef _Float16 h16;
typedef __attribute__((ext_vector_type(8))) _Float16 h16x8;
typedef __attribute__((ext_vector_type(4))) _Float16 h16x4;
typedef __attribute__((ext_vector_type(2))) _Float16 h16x2;
typedef __attribute__((ext_vector_type(4))) float    f32x4;
typedef __attribute__((ext_vector_type(2))) float    f32x2;

__device__ __forceinline__ float fast_tanh(float z) {
  float e = __builtin_amdgcn_exp2f(z * 2.8853900817779268f);
  return 1.0f - 2.0f * __builtin_amdgcn_rcpf(e + 1.0f);
}

__device__ __forceinline__ h16x8 cvt8(const float* __restrict__ p) {
  f32x4 f0 = *(const f32x4*)p;
  f32x4 f1 = *(const f32x4*)(p + 4);
  h16x8 a;
  #pragma unroll
  for (int j = 0; j < 4; ++j) { a[j] = (h16)f0[j]; a[4 + j] = (h16)f1[j]; }
  return a;
}

// ---------------- Prologue: xp = W_ih x + b_ih + b_hh, permuted f16 ----------
// chunk ((t*16+g)*8+wave)*64+lane holds 16 h16:
// [m*4+i] = xp[batch=16g+(lane&15)][t][col=64*wave+16m+4*(lane>>4)+i]
__global__ __launch_bounds__(512)
void xp_gemm(const float* __restrict__ x, const float* __restrict__ Wih,
             const float* __restrict__ bih, const float* __restrict__ bhh,
             h16* __restrict__ xp, unsigned* __restrict__ cnt)
{
  const int tid  = threadIdx.x;
  const int wave = tid >> 6;
  const int lane = tid & 63;
  const int lr   = lane & 15;
  const int lk   = lane >> 4;
  const int blk  = blockIdx.x & 15;
  const int tc   = blockIdx.x >> 4;
  const int c0   = wave * 64;

  if (cnt && blockIdx.x == 0 && tid < 64) cnt[tid] = 0u;  // graph-replay-safe re-init

  h16x8 A[4][2];
  #pragma unroll
  for (int m = 0; m < 4; ++m)
    #pragma unroll
    for (int s = 0; s < 2; ++s)
      A[m][s] = cvt8(Wih + (size_t)(c0 + 16 * m + lr) * NIN + 32 * s + 8 * lk);

  f32x4 bias[4];
  #pragma unroll
  for (int m = 0; m < 4; ++m) {
    const int c = c0 + 16 * m + 4 * lk;
    f32x4 bi = *(const f32x4*)&bih[c];
    f32x4 bh = *(const f32x4*)&bhh[c];
    bias[m] = bi + bh;
  }

  const float* xrow = x + (size_t)(16 * blk + lr) * (TSTEPS * NIN);

  for (int j = 0; j < 32; ++j) {
    const int t = tc * 32 + j;
    f32x4 acc[4];
    #pragma unroll
    for (int m = 0; m < 4; ++m) acc[m] = bias[m];
    #pragma unroll
    for (int s = 0; s < 2; ++s) {
      h16x8 bx = cvt8(xrow + (size_t)t * NIN + 32 * s + 8 * lk);
      #pragma unroll
      for (int m = 0; m < 4; ++m)
        acc[m] = __builtin_amdgcn_mfma_f32_16x16x32_f16(A[m][s], bx, acc[m], 0, 0, 0);
    }
    h16x8 c0v, c1v;
    #pragma unroll
    for (int i = 0; i < 4; ++i) {
      c0v[i]     = (h16)acc[0][i];
      c0v[4 + i] = (h16)acc[1][i];
      c1v[i]     = (h16)acc[2][i];
      c1v[4 + i] = (h16)acc[3][i];
    }
    h16* p = xp + ((((size_t)t * 16 + blk) * 8 + wave) * 64 + lane) * 16;
    *(h16x8*)p       = c0v;
    *(h16x8*)(p + 8) = c1v;
  }
}

// ---------------- Path A2: K-split recurrence --------------------------------
__global__ __launch_bounds__(512, 2)
void rnn_core2(const float* __restrict__ Whh, const h16* __restrict__ xp,
               h16* __restrict__ hall, float* __restrict__ ex,
               unsigned* __restrict__ cnt)
{
  __shared__ h16 hl[2][16 * HPAD2];   // 16896 B: [buf][batch_row][k-local col]

  const int tid  = threadIdx.x;
  const int wave = tid >> 6;
  const int lane = tid & 63;
  const int lr   = lane & 15;
  const int lk   = lane >> 4;
  const int kb   = blockIdx.x >> 4;       // k-half owned by this block
  const int g    = blockIdx.x & 15;       // batch group
  const int wq   = wave & 3;
  const bool fin = ((wave >> 2) == kb);   // finalizer: cols lie in own k-half
  const int b0   = g * 16;

  // A-frags: cols c = 64*wave+16m+lr (all 512 across 8 waves), k-half kb.
  // 32 slots x 4 regs = 128 VGPRs.
  h16x8 areg[8][4];   // [s][m]
  #pragma unroll
  for (int s = 0; s < 8; ++s)
    #pragma unroll
    for (int m = 0; m < 4; ++m)
      areg[s][m] = cvt8(Whh + (size_t)(64 * wave + 16 * m + lr) * HDIM
                        + KHALF * kb + 32 * s + 8 * lk);

  for (int idx = tid; idx < 16 * HPAD2; idx += 512) hl[0][idx] = (h16)0.f;
  __syncthreads();

  // xp preload (finalizers only; their cols = their xp chunk)
  h16x8 xr0, xr1;
  if (fin) {
    const h16* p = xp + (((size_t)g * 8 + wave) * 64 + lane) * 16;
    xr0 = *(const h16x8*)p;
    xr1 = *(const h16x8*)(p + 8);
  }

  unsigned* mycnt   = &cnt[g * 2 + kb];
  unsigned* partcnt = &cnt[g * 2 + (1 - kb)];

  for (int t = 0; t < TSTEPS; ++t) {
    f32x4 acc[4];
    if (fin) {
      #pragma unroll
      for (int i = 0; i < 4; ++i) {
        acc[0][i] = (float)xr0[i];
        acc[1][i] = (float)xr0[4 + i];
        acc[2][i] = (float)xr1[i];
        acc[3][i] = (float)xr1[4 + i];
      }
      const int tn = (t + 1 < TSTEPS) ? (t + 1) : t;
      const h16* p = xp + ((((size_t)tn * 16 + g) * 8 + wave) * 64 + lane) * 16;
      xr0 = *(const h16x8*)p;
      xr1 = *(const h16x8*)(p + 8);
    } else {
      #pragma unroll
      for (int m = 0; m < 4; ++m) { acc[m][0]=0.f; acc[m][1]=0.f; acc[m][2]=0.f; acc[m][3]=0.f; }
    }

    // partials over own k-half (h-local layout == own k range)
    const h16* hb = hl[t & 1];
    #pragma unroll
    for (int s = 0; s < 8; ++s) {
      h16x8 bh = *(const h16x8*)&hb[lr * HPAD2 + 32 * s + 8 * lk];
      #pragma unroll
      for (int m = 0; m < 4; ++m)
        acc[m] = __builtin_amdgcn_mfma_f32_16x16x32_f16(areg[s][m], bh, acc[m], 0, 0, 0);
    }

    if (!fin) {
      // send partials for the partner's cols
      float* exw = ex + ((size_t)((g * 2 + kb) * 2 + (t & 1)) << 12);
      #pragma unroll
      for (int m = 0; m < 4; ++m)
        *(f32x4*)&exw[((wq * 16 + m * 4 + lk) << 6) + lr * 4] = acc[m];
      if (lane == 0)
        __hip_atomic_fetch_add(mycnt, 1u, __ATOMIC_RELEASE, __HIP_MEMORY_SCOPE_AGENT);
    } else {
      // receive partner partials for own cols, finalize h
      const unsigned tgt = 4u * (unsigned)(t + 1);
      while (__hip_atomic_load(partcnt, __ATOMIC_ACQUIRE, __HIP_MEMORY_SCOPE_AGENT) < tgt)
        __builtin_amdgcn_s_sleep(1);
      const float* exr = ex + ((size_t)((g * 2 + (1 - kb)) * 2 + (t & 1)) << 12);
      h16* hn   = hl[(t + 1) & 1];
      h16* hrow = hall + ((size_t)t * 256 + b0 + lr) * HDIM + KHALF * kb + 64 * wq + 4 * lk;
      #pragma unroll
      for (int m = 0; m < 4; ++m) {
        f32x4 pp = *(const f32x4*)&exr[((wq * 16 + m * 4 + lk) << 6) + lr * 4];
        h16x4 hv;
        #pragma unroll
        for (int i = 0; i < 4; ++i) hv[i] = (h16)fast_tanh(acc[m][i] + pp[i]);
        *(h16x4*)&hn[lr * HPAD2 + 64 * wq + 16 * m + 4 * lk] = hv;
        *(h16x4*)(hrow + 16 * m) = hv;
      }
    }

    __syncthreads();
  }
}

// ---------------- Epilogue: out = tanh(h_all @ W_ho^T + b_ho) ----------------
__global__ __launch_bounds__(512)
void out_all(const h16* __restrict__ hall, const float* __restrict__ Who,
             const float* __restrict__ bho, float* __restrict__ out)
{
  __shared__ h16 wholds[NOUT * HPAD];   // 24960 B

  const int tid  = threadIdx.x;
  const int wave = tid >> 6;
  const int lane = tid & 63;
  const int lr   = lane & 15;
  const int lk   = lane >> 4;

  for (int idx = tid; idx < NOUT * HDIM; idx += 512) {
    int r = idx >> 9, k = idx & 511;
    wholds[r * HPAD + k] = (h16)Who[idx];
  }

  f32x4 o0, o1;
  { o0 = *(const f32x4*)&bho[lk * 4]; }
  { int ob = 16 + lk * 4;
    if (ob < NOUT) o1 = *(const f32x4*)&bho[ob];
    else { o1[0] = 0.f; o1[1] = 0.f; o1[2] = 0.f; o1[3] = 0.f; } }
  __syncthreads();

  const int rt = blockIdx.x * 8 + wave;
  const int t  = rt >> 4;
  const int b  = (rt & 15) * 16 + lr;
  const int row1 = (16 + lr < NOUT) ? (16 + lr) : (8 + lr);

  const h16* hrow = hall + ((size_t)t * 256 + b) * HDIM + lk * 8;

  #pragma unroll
  for (int s = 0; s < 16; ++s) {
    h16x8 bh = *(const h16x8*)(hrow + 32 * s);
    h16x8 a0 = *(const h16x8*)&wholds[lr * HPAD + s * 32 + lk * 8];
    h16x8 a1 = *(const h16x8*)&wholds[row1 * HPAD + s * 32 + lk * 8];
    o0 = __builtin_amdgcn_mfma_f32_16x16x32_f16(a0, bh, o0, 0, 0, 0);
    o1 = __builtin_amdgcn_mfma_f32_16x16x32_f16(a1, bh, o1, 0, 0, 0);
  }

  float* op = out + ((size_t)b * TSTEPS + t) * NOUT;
  f32x4 v0;
  #pragma unroll
  for (int i = 0; i < 4; ++i) v0[i] = fast_tanh(o0[i]);
  *(f32x4*)(op + lk * 4) = v0;
  if (lk < 2) {
    f32x4 v1;
    #pragma unroll
    for (int i = 0; i < 4; ++i) v1[i] = fast_tanh(o1[i]);
    *(f32x4*)(op + 16 + lk * 4) = v1;
  }
}

// ---------------- Path A fallback: round-3 single-CU recurrence --------------
__global__ __launch_bounds__(512, 2)
void rnn_core(const float* __restrict__ Whh, const h16* __restrict__ xp,
              h16* __restrict__ hall)
{
  __shared__ h16 hbuf[2][BB * HPAD];
  __shared__ h16 aslice[NLDS * 8 * 512];

  const int tid  = threadIdx.x;
  const int wave = tid >> 6;
  const int lane = tid & 63;
  const int lr   = lane & 15;
  const int lk   = lane >> 4;
  const int blk  = blockIdx.x;
  const int b0   = blk * BB;
  const int wc0  = wave * 64;

  h16x8 areg[NREG];
  #pragma unroll
  for (int s = 0; s < 16; ++s) {
    #pragma unroll
    for (int m = 0; m < 4; ++m) {
      h16x8 a = cvt8(Whh + (size_t)(wc0 + 16 * m + lr) * HDIM + 32 * s + 8 * lk);
      const int id = s * 4 + m;
      if (id < NREG) areg[id] = a;
      else *(h16x8*)&aslice[(size_t)((id - NREG) * 8 + wave) * 512 + lane * 8] = a;
    }
  }

  for (int idx = tid; idx < BB * HPAD; idx += 512) hbuf[0][idx] = (h16)0.f;
  __syncthreads();

  h16x8 xr0, xr1;
  {
    const h16* p = xp + (((size_t)blk * 8 + wave) * 64 + lane) * 16;
    xr0 = *(const h16x8*)p;
    xr1 = *(const h16x8*)(p + 8);
  }

  for (int t = 0; t < TSTEPS; ++t) {
    const h16* hb = hbuf[t & 1];
    h16*       hn = hbuf[(t + 1) & 1];

    f32x4 acc[4];
    #pragma unroll
    for (int i = 0; i < 4; ++i) {
      acc[0][i] = (float)xr0[i];
      acc[1][i] = (float)xr0[4 + i];
      acc[2][i] = (float)xr1[i];
      acc[3][i] = (float)xr1[4 + i];
    }
    {
      const int tn = (t + 1 < TSTEPS) ? (t + 1) : t;
      const h16* p = xp + ((((size_t)tn * 16 + blk) * 8 + wave) * 64 + lane) * 16;
      xr0 = *(const h16x8*)p;
      xr1 = *(const h16x8*)(p + 8);
    }

    #pragma unroll
    for (int s = 0; s < 16; ++s) {
      h16x8 bh = *(const h16x8*)&hb[lr * HPAD + 32 * s + 8 * lk];
      #pragma unroll
      for (int m = 0; m < 4; ++m) {
        const int id = s * 4 + m;
        h16x8 a = (id < NREG)
            ? areg[id]
            : *(const h16x8*)&aslice[(size_t)((id - NREG) * 8 + wave) * 512 + lane * 8];
        acc[m] = __builtin_amdgcn_mfma_f32_16x16x32_f16(a, bh, acc[m], 0, 0, 0);
      }
    }

    h16* hrow = hall + ((size_t)t * 256 + b0 + lr) * HDIM + wc0 + lk * 4;
    #pragma unroll
    for (int m = 0; m < 4; ++m) {
      h16x4 hv;
      #pragma unroll
      for (int i = 0; i < 4; ++i) hv[i] = (h16)fast_tanh(acc[m][i]);
      *(h16x4*)&hn[lr * HPAD + wc0 + 16 * m + 4 * lk] = hv;
      *(h16x4*)(hrow + 16 * m) = hv;
    }

    __syncthreads();
  }
}

// ---------------- Path C: fully self-contained fallback ----------------------
__device__ __forceinline__ void out_proj(
    int t, const h16* __restrict__ hb, const h16* __restrict__ who,
    f32x4 bho0, f32x4 bho1, float* __restrict__ out, int b0, int lr, int lk)
{
  f32x4 o0 = bho0, o1 = bho1;
  const int row1 = (16 + lr < NOUT) ? (16 + lr) : (8 + lr);
  #pragma unroll
  for (int s = 0; s < 16; ++s) {
    h16x8 bh = *(const h16x8*)&hb[lr * HPAD + s * 32 + lk * 8];
    h16x8 a0 = *(const h16x8*)&who[lr * HPAD + s * 32 + lk * 8];
    h16x8 a1 = *(const h16x8*)&who[row1 * HPAD + s * 32 + lk * 8];
    o0 = __builtin_amdgcn_mfma_f32_16x16x32_f16(a0, bh, o0, 0, 0, 0);
    o1 = __builtin_amdgcn_mfma_f32_16x16x32_f16(a1, bh, o1, 0, 0, 0);
  }
  float* op = out + ((size_t)(b0 + lr) * TSTEPS + t) * NOUT;
  f32x4 v0;
  #pragma unroll
  for (int i = 0; i < 4; ++i) v0[i] = fast_tanh(o0[i]);
  *(f32x4*)(op + lk * 4) = v0;
  if (lk < 2) {
    f32x4 v1;
    #pragma unroll
    for (int i = 0; i < 4; ++i) v1[i] = fast_tanh(o1[i]);
    *(f32x4*)(op + 16 + lk * 4) = v1;
  }
}

__global__ __launch_bounds__(512, 2)
void rnn_fused(const float* __restrict__ x,
               const float* __restrict__ Wih,
               const float* __restrict__ Whh,
               const float* __restrict__ bih,
               const float* __restrict__ bhh,
               const float* __restrict__ Who,
               const float* __restrict__ bho,
               float* __restrict__ out)
{
  __shared__ h16 hbuf[2][BB * HPAD];
  __shared__ h16 xbuf[2][BB * XPAD];
  __shared__ h16 wholds[NOUT * HPAD];

  const int tid  = threadIdx.x;
  const int wave = tid >> 6;
  const int lane = tid & 63;
  const int lr   = lane & 15;
  const int lk   = lane >> 4;
  const int b0   = blockIdx.x * BB;
  const int wc0  = wave * 64;

  h16x8 a_rec[4][16];
  #pragma unroll
  for (int m = 0; m < 4; ++m) {
    const int row = wc0 + m * 16 + lr;
    #pragma unroll
    for (int s = 0; s < 16; ++s)
      a_rec[m][s] = cvt8(Whh + (size_t)row * HDIM + s * 32 + lk * 8);
  }
  h16x8 a_ih[4][2];
  #pragma unroll
  for (int m = 0; m < 4; ++m) {
    const int row = wc0 + m * 16 + lr;
    #pragma unroll
    for (int s = 0; s < 2; ++s)
      a_ih[m][s] = cvt8(Wih + (size_t)row * NIN + s * 32 + lk * 8);
  }
  f32x4 biasv[4];
  #pragma unroll
  for (int m = 0; m < 4; ++m) {
    const int c = wc0 + m * 16 + lk * 4;
    f32x4 bi = *(const f32x4*)&bih[c];
    f32x4 bh2 = *(const f32x4*)&bhh[c];
    biasv[m] = bi + bh2;
  }
  f32x4 bho0, bho1;
  { bho0 = *(const f32x4*)&bho[lk * 4]; }
  { int ob = 16 + lk * 4;
    if (ob < NOUT) bho1 = *(const f32x4*)&bho[ob];
    else { bho1[0] = 0.f; bho1[1] = 0.f; bho1[2] = 0.f; bho1[3] = 0.f; } }

  for (int idx = tid; idx < NOUT * HDIM; idx += 512) {
    int r = idx >> 9, k = idx & 511;
    wholds[r * HPAD + k] = (h16)Who[idx];
  }
  for (int idx = tid; idx < BB * HPAD; idx += 512) hbuf[0][idx] = (h16)0.f;
  {
    int r = tid >> 5, c2 = (tid & 31) * 2;
    f32x2 v = *(const f32x2*)(x + ((size_t)(b0 + r) * TSTEPS + 0) * NIN + c2);
    h16x2 pk = { (h16)v.x, (h16)v.y };
    *(h16x2*)&xbuf[0][r * XPAD + c2] = pk;
  }
  __syncthreads();

  for (int t = 0; t < TSTEPS; ++t) {
    const h16* hb = hbuf[t & 1];
    h16*       hn = hbuf[(t + 1) & 1];
    const h16* xb = xbuf[t & 1];
    h16*       xn = xbuf[(t + 1) & 1];

    if (t > 0 && wave == ((t - 1) & 7))
      out_proj(t - 1, hb, wholds, bho0, bho1, out, b0, lr, lk);

    const int tl = (t + 1 < TSTEPS) ? (t + 1) : (TSTEPS - 1);
    const int xr = tid >> 5, xc = (tid & 31) * 2;
    f32x2 xv = *(const f32x2*)(x + ((size_t)(b0 + xr) * TSTEPS + tl) * NIN + xc);

    f32x4 acc[4];
    #pragma unroll
    for (int m = 0; m < 4; ++m) acc[m] = biasv[m];
    #pragma unroll
    for (int s = 0; s < 2; ++s) {
      h16x8 bx = *(const h16x8*)&xb[lr * XPAD + s * 32 + lk * 8];
      #pragma unroll
      for (int m = 0; m < 4; ++m)
        acc[m] = __builtin_amdgcn_mfma_f32_16x16x32_f16(a_ih[m][s], bx, acc[m], 0, 0, 0);
    }
    #pragma unroll
    for (int s = 0; s < 16; ++s) {
      h16x8 bh = *(const h16x8*)&hb[lr * HPAD + 32 * s + 8 * lk];
      #pragma unroll
      for (int m = 0; m < 4; ++m)
        acc[m] = __builtin_amdgcn_mfma_f32_16x16x32_f16(a_rec[m][s], bh, acc[m], 0, 0, 0);
    }
    #pragma unroll
    for (int m = 0; m < 4; ++m) {
      h16x4 hv;
      #pragma unroll
      for (int i = 0; i < 4; ++i) hv[i] = (h16)fast_tanh(acc[m][i]);
      *(h16x4*)&hn[lr * HPAD + wc0 + 16 * m + 4 * lk] = hv;
    }
    {
      h16x2 pk = { (h16)xv.x, (h16)xv.y };
      *(h16x2*)&xn[xr * XPAD + xc] = pk;
    }
    __syncthreads();
  }

  if (wave == ((TSTEPS - 1) & 7))
    out_proj(TSTEPS - 1, hbuf[TSTEPS & 1], wholds, bho0, bho1, out, b0, lr, lk);
}

extern "C" void kernel_launch(void* const* d_in, const int* in_sizes, int n_in,
                              void* d_out, int out_size, void* d_ws, size_t ws_size,
                              hipStream_t stream) {
  (void)in_sizes; (void)n_in; (void)out_size;
  const float* x   = (const float*)d_in[0];
  const float* Wih = (const float*)d_in[1];
  const float* Whh = (const float*)d_in[2];
  const float* bih = (const float*)d_in[3];
  const float* bhh = (const float*)d_in[4];
  const float* Who = (const float*)d_in[5];
  const float* bho = (const float*)d_in[6];
  float* out = (float*)d_out;

  const size_t XP_BYTES   = (size_t)TSTEPS * 256 * HDIM * sizeof(h16);  // 128 MiB
  const size_t HALL_BYTES = (size_t)TSTEPS * 256 * HDIM * sizeof(h16);  // 128 MiB
  const size_t EX_BYTES   = (size_t)64 * 4096 * sizeof(float);          // 1 MiB
  const size_t CNT_BYTES  = 64 * sizeof(unsigned);

  if (ws_size >= XP_BYTES + HALL_BYTES + EX_BYTES + CNT_BYTES) {
    h16*      xp   = (h16*)d_ws;
    h16*      hall = (h16*)((char*)d_ws + XP_BYTES);
    float*    ex   = (float*)((char*)d_ws + XP_BYTES + HALL_BYTES);
    unsigned* cnt  = (unsigned*)((char*)d_ws + XP_BYTES + HALL_BYTES + EX_BYTES);
    xp_gemm<<<dim3(256), dim3(512), 0, stream>>>(x, Wih, bih, bhh, xp, cnt);
    rnn_core2<<<dim3(32), dim3(512), 0, stream>>>(Whh, xp, hall, ex, cnt);
    out_all<<<dim3(1024), dim3(512), 0, stream>>>(hall, Who, bho, out);
  } else if (ws_size >= XP_BYTES + HALL_BYTES) {
    h16* xp   = (h16*)d_ws;
    h16* hall = (h16*)((char*)d_ws + XP_BYTES);
    xp_gemm<<<dim3(256), dim3(512), 0, stream>>>(x, Wih, bih, bhh, xp, nullptr);
    rnn_core<<<dim3(256 / BB), dim3(512), 0, stream>>>(Whh, xp, hall);
    out_all<<<dim3(1024), dim3(512), 0, stream>>>(hall, Who, bho, out);
  } else {
    rnn_fused<<<dim3(256 / BB), dim3(512), 0, stream>>>(x, Wih, Whh, bih, bhh, Who, bho, out);
  }
}